// Round 5
// baseline (1382.254 us; speedup 1.0000x reference)
//
#include <hip/hip_runtime.h>

// Residual VQ, bit-exact replication of the numpy reference's fp32 rounding.
// B=16 S=2048 D=64 K=8 M=2048.
//
// Numerics contract (verified bit-exact, absmax 0.0):
//  - r2/c2: numpy pairwise_sum 8-accumulator order, no FMA contraction
//  - cross: numpy einsum baseline-SSE order: 4 chains (d mod 4), per 16-block
//           groups at offsets {12,8,4,0}+j, blocks ascending, hsum (L0+L1)+(L2+L3)
//  - t = fl(r2 - 2*cross) via fma(-2,cross,r2); d2 = fl(t + c2)
//  - argmin: first occurrence == u64-min over key {d2_bits(hi), m(lo)} (d2>0)
//
// R10 transport model (fits R5-R9 quantitatively):
//  - scalar K$ shared per 4 CUs, ~5 cy/REQUEST (width-independent; R8 sharing
//    null because hits pay the port too). R5: 5req*16w*4CU*5 = 1600 ~ 1725 obs.
//  - VMEM ~17 cy/instr per CU even for broadcast (R6: 2312 pred / 2334 obs).
//  - LDS broadcast ds_read_b128 ~12 cy (R9: 1536 pred / 1638 obs, LDS-bound).
//  - VALU floor: 4 waves/SIMD x 268 cy = 1072 cy per CU-row-window.
// Per-row budgets: scalar <=3.3 req, LDS <=5.6 b128, VMEM <=3.9 dwordx4.
// R10 split: SMEM d0..31 (2 dwordx16 + c2 = 3 req, P/Q ping-pong s[32:95]),
// LDS d32..51 ([256][20] 20KB staged, 5 ds_read_b128 -> v[96:115]),
// VMEM d52..63 (3 broadcast dwordx4 -> v[116:127], single-buffer,
// issue-after-consume with one-einsum+4-wave-TLP lead, vmcnt(0) exact).
// All pipes <= VALU window; registers exactly 128 (4 waves/SIMD tier).
// Einsum instruction sequence operand-identical -> bit-exact preserved.

#define BB 16
#define SS 2048
#define DD 64
#define KK 8
#define MM 2048
#define NPTS (BB * SS)      // 32768
#define QSIZE (NPTS * DD)   // 2097152
#define NCHUNK 8
#define WPB 8               // waves per block (all same chunk)
#define PPB 512             // points per block
#define MCHUNK (MM / NCHUNK)  // 256 rows per chunk

// ---- prep: c2[k][m] (numpy pairwise) + key init ----
__global__ __launch_bounds__(256) void rvq_prep(const float* __restrict__ cb,
                                                float* __restrict__ c2,
                                                unsigned long long* __restrict__ keys) {
#pragma clang fp contract(off)
    int tid = blockIdx.x * 256 + threadIdx.x;  // 0 .. K*M-1 = 16383
    const float* row = cb + (size_t)tid * DD;
    float r[8];
#pragma unroll
    for (int j = 0; j < 8; ++j) { float v = row[j]; r[j] = v * v; }
#pragma unroll
    for (int i = 8; i < DD; i += 8) {
#pragma unroll
        for (int j = 0; j < 8; ++j) { float v = row[i + j]; float t = v * v; r[j] += t; }
    }
    c2[tid] = ((r[0] + r[1]) + (r[2] + r[3])) + ((r[4] + r[5]) + (r[6] + r[7]));
    keys[tid] = ~0ULL;                 // NPTS = 2 * K*M
    keys[tid + KK * MM] = ~0ULL;
}

// r2 chain block for k-th 8-float group (bases A=16+8k, etc.)
#define R2K(A, B, C, E) \
    "v_pk_mul_f32 v[92:93], v[" A "], v[" A "]\n\t" \
    "v_pk_add_f32 v[80:81], v[80:81], v[92:93]\n\t" \
    "v_pk_mul_f32 v[92:93], v[" B "], v[" B "]\n\t" \
    "v_pk_add_f32 v[82:83], v[82:83], v[92:93]\n\t" \
    "v_pk_mul_f32 v[92:93], v[" C "], v[" C "]\n\t" \
    "v_pk_add_f32 v[84:85], v[84:85], v[92:93]\n\t" \
    "v_pk_mul_f32 v[92:93], v[" E "], v[" E "]\n\t" \
    "v_pk_add_f32 v[86:87], v[86:87], v[92:93]\n\t"

// einsum group, codebook from SGPR pairs
#define GRP(SA, SB, VA, VB) \
    "v_pk_mul_f32 v[84:85], s[" SA "], v[" VA "]\n\t" \
    "v_pk_mul_f32 v[86:87], s[" SB "], v[" VB "]\n\t" \
    "v_pk_add_f32 v[80:81], v[80:81], v[84:85]\n\t" \
    "v_pk_add_f32 v[82:83], v[82:83], v[86:87]\n\t"

// einsum group, codebook from VGPR pairs (LDS/VMEM-transported)
#define GRPL(CA, CB, VA, VB) \
    "v_pk_mul_f32 v[84:85], v[" CA "], v[" VA "]\n\t" \
    "v_pk_mul_f32 v[86:87], v[" CB "], v[" VB "]\n\t" \
    "v_pk_add_f32 v[80:81], v[80:81], v[84:85]\n\t" \
    "v_pk_add_f32 v[82:83], v[82:83], v[86:87]\n\t"

// issue SMEM (d0..31, 128B = 2 dwordx16) + c2 into buffer; clamped ptr s29
#define SMEMLD(BA, BB, C2D) \
    "s_min_u32 s30, s29, 0xff00\n\t" \
    "s_load_dwordx16 s[" BA "], %[cb], s30\n\t" \
    "s_add_u32 s25, s30, 64\n\t" \
    "s_load_dwordx16 s[" BB "], %[cb], s25\n\t" \
    "s_lshr_b32 s25, s30, 6\n\t" \
    "s_load_dword " C2D ", %[c2], s25\n\t" \
    "s_add_u32 s29, s29, 256\n\t"

// issue LDS (d32..51, 80B = 5 b128) broadcast -> v[96:115]; advance+clamp v94
#define DSLD5 \
    "ds_read_b128 v[96:99],   v94\n\t" \
    "ds_read_b128 v[100:103], v94 offset:16\n\t" \
    "ds_read_b128 v[104:107], v94 offset:32\n\t" \
    "ds_read_b128 v[108:111], v94 offset:48\n\t" \
    "ds_read_b128 v[112:115], v94 offset:64\n\t" \
    "v_add_u32 v94, 0x50, v94\n\t" \
    "v_min_u32 v94, %[lc], v94\n\t"

// einsum b0+b16 from SMEM P buffer s[32:63]
#define EINSM_P \
    "v_pk_mul_f32 v[80:81], s[44:45], v[28:29]\n\t" \
    "v_pk_mul_f32 v[82:83], s[46:47], v[30:31]\n\t" \
    GRP("40:41","42:43","24:25","26:27") \
    GRP("36:37","38:39","20:21","22:23") \
    GRP("32:33","34:35","16:17","18:19") \
    GRP("60:61","62:63","44:45","46:47") \
    GRP("56:57","58:59","40:41","42:43") \
    GRP("52:53","54:55","36:37","38:39") \
    GRP("48:49","50:51","32:33","34:35")

// einsum b0+b16 from SMEM Q buffer s[64:95]
#define EINSM_Q \
    "v_pk_mul_f32 v[80:81], s[76:77], v[28:29]\n\t" \
    "v_pk_mul_f32 v[82:83], s[78:79], v[30:31]\n\t" \
    GRP("72:73","74:75","24:25","26:27") \
    GRP("68:69","70:71","20:21","22:23") \
    GRP("64:65","66:67","16:17","18:19") \
    GRP("92:93","94:95","44:45","46:47") \
    GRP("88:89","90:91","40:41","42:43") \
    GRP("84:85","86:87","36:37","38:39") \
    GRP("80:81","82:83","32:33","34:35")

// einsum b32 (LDS) + b48 (VMEM d60,56,52 then LDS d48); issues next-row VMEM
// right after its last consumer (one-einsum issue lead, vmcnt(0) exact).
#define EIN_TAIL \
    GRPL("108:109","110:111","60:61","62:63") \
    GRPL("104:105","106:107","56:57","58:59") \
    GRPL("100:101","102:103","52:53","54:55") \
    GRPL("96:97","98:99","48:49","50:51") \
    "s_waitcnt vmcnt(0)\n\t" \
    GRPL("124:125","126:127","76:77","78:79") \
    GRPL("120:121","122:123","72:73","74:75") \
    GRPL("116:117","118:119","68:69","70:71") \
    "global_load_dwordx4 v[116:119], v95, %[cb] offset:208\n\t" \
    "global_load_dwordx4 v[120:123], v95, %[cb] offset:224\n\t" \
    "global_load_dwordx4 v[124:127], v95, %[cb] offset:240\n\t" \
    "v_add_u32 v95, 0x100, v95\n\t" \
    "v_min_u32 v95, 0xff00, v95\n\t" \
    GRPL("112:113","114:115","64:65","66:67")

// hsum, d2, argmin update; C2S = SGPR holding c2 of this row
#define FINX(C2S) \
    "v_add_f32 v92, v80, v81\n\t" \
    "v_add_f32 v93, v82, v83\n\t" \
    "v_add_f32 v92, v92, v93\n\t" \
    "v_fma_f32 v92, v92, -2.0, v88\n\t" \
    "v_add_f32 v92, " C2S ", v92\n\t" \
    "v_cmp_lt_f32 vcc, v92, v89\n\t" \
    "v_cndmask_b32 v89, v89, v92, vcc\n\t" \
    "v_cndmask_b32 v90, v90, v91, vcc\n\t" \
    "v_add_u32 v91, 1, v91\n\t"

// ---- main: per-chunk argmin, atomicMin-combined ----
// grid = 512 blocks x 512 threads (8 waves). Block b: chunk = b & 7,
// point-group = b >> 3. 2 blocks/CU, 4 waves/SIMD, 20KB LDS/block.
__global__ __launch_bounds__(512, 4) void rvq_main(const float* __restrict__ res_in,
                                                   const float* __restrict__ cbk,  // (M,D)
                                                   const float* __restrict__ c2k,  // (M,)
                                                   unsigned long long* __restrict__ keys) {
#pragma clang fp contract(off)
    const int tid = threadIdx.x;
    const int lane = tid & 63;
    const int wv = __builtin_amdgcn_readfirstlane(tid >> 6);  // 0..7
    const int ch = blockIdx.x & (NCHUNK - 1);
    const int bp = blockIdx.x >> 3;
    const int point = bp * PPB + wv * 64 + lane;

    const int m0 = ch * MCHUNK;
    const float* cbw = cbk + (size_t)m0 * DD;   // this block's chunk base
    const float* c2w = c2k + m0;
    const unsigned long long ra = (unsigned long long)(res_in + (size_t)point * DD);

    // ---- stage d=32..51 of the chunk into LDS: [256 rows][20 floats] ----
    __shared__ __align__(16) float lds_cb[MCHUNK * 20];   // 20 KB
    for (int i = tid; i < MCHUNK * 5; i += PPB) {         // 1280 float4s
        const int row = i / 5;
        const int j = i - row * 5;
        *(float4*)&lds_cb[row * 20 + j * 4] =
            *(const float4*)(cbw + row * DD + 32 + j * 4);
    }
    __syncthreads();
    const unsigned ldsbase = (unsigned)(unsigned long long)(void*)&lds_cb[0];
    const unsigned ldsclamp = ldsbase + (MCHUNK - 1) * 80;

    float best;
    int bidx;
    asm volatile(
        // ---- residual: 64 floats -> v[16:79]; v95 pre-init for V prime ----
        "v_mov_b32 v95, 0\n\t"
        "global_load_dwordx4 v[16:19], %[ra], off\n\t"
        "global_load_dwordx4 v[20:23], %[ra], off offset:16\n\t"
        "global_load_dwordx4 v[24:27], %[ra], off offset:32\n\t"
        "global_load_dwordx4 v[28:31], %[ra], off offset:48\n\t"
        "global_load_dwordx4 v[32:35], %[ra], off offset:64\n\t"
        "global_load_dwordx4 v[36:39], %[ra], off offset:80\n\t"
        "global_load_dwordx4 v[40:43], %[ra], off offset:96\n\t"
        "global_load_dwordx4 v[44:47], %[ra], off offset:112\n\t"
        "global_load_dwordx4 v[48:51], %[ra], off offset:128\n\t"
        "global_load_dwordx4 v[52:55], %[ra], off offset:144\n\t"
        "global_load_dwordx4 v[56:59], %[ra], off offset:160\n\t"
        "global_load_dwordx4 v[60:63], %[ra], off offset:176\n\t"
        "global_load_dwordx4 v[64:67], %[ra], off offset:192\n\t"
        "global_load_dwordx4 v[68:71], %[ra], off offset:208\n\t"
        "global_load_dwordx4 v[72:75], %[ra], off offset:224\n\t"
        "global_load_dwordx4 v[76:79], %[ra], off offset:240\n\t"
        "s_waitcnt vmcnt(0)\n\t"
        // ---- prime VMEM row 0 (latency covered by r2 compute) ----
        "global_load_dwordx4 v[116:119], v95, %[cb] offset:208\n\t"
        "global_load_dwordx4 v[120:123], v95, %[cb] offset:224\n\t"
        "global_load_dwordx4 v[124:127], v95, %[cb] offset:240\n\t"
        "v_mov_b32 v95, 0x100\n\t"
        // ---- r2, numpy pairwise 8-acc order; accs in v[80:87] ----
        "v_pk_mul_f32 v[80:81], v[16:17], v[16:17]\n\t"
        "v_pk_mul_f32 v[82:83], v[18:19], v[18:19]\n\t"
        "v_pk_mul_f32 v[84:85], v[20:21], v[20:21]\n\t"
        "v_pk_mul_f32 v[86:87], v[22:23], v[22:23]\n\t"
        R2K("24:25", "26:27", "28:29", "30:31")
        R2K("32:33", "34:35", "36:37", "38:39")
        R2K("40:41", "42:43", "44:45", "46:47")
        R2K("48:49", "50:51", "52:53", "54:55")
        R2K("56:57", "58:59", "60:61", "62:63")
        R2K("64:65", "66:67", "68:69", "70:71")
        R2K("72:73", "74:75", "76:77", "78:79")
        "v_add_f32 v92, v80, v81\n\t"
        "v_add_f32 v93, v82, v83\n\t"
        "v_add_f32 v92, v92, v93\n\t"
        "v_add_f32 v93, v84, v85\n\t"
        "v_add_f32 v88, v86, v87\n\t"
        "v_add_f32 v93, v93, v88\n\t"
        "v_add_f32 v88, v92, v93\n\t"          // r2 -> v88
        // ---- init ----
        "v_mov_b32 v89, 0x7f800000\n\t"        // best = +inf
        "v_mov_b32 v90, 0\n\t"                 // bidx = 0
        "v_mov_b32 v91, %[m0]\n\t"             // current m
        "v_mov_b32 v94, %[lb]\n\t"             // LDS read ptr (row 0)
        "s_mov_b32 s29, 0\n\t"                 // SMEM prefetch byte offset
        SMEMLD("32:47", "48:63", "s26")        // P(0); s29 -> 256
        DSLD5                                  // ds(0); v94 -> row 1
        "s_mov_b32 s24, 0\n\t"                 // row-pair counter
        "Ltop_%=:\n\t"
        // ---- row r (even, buffer P): in flight on entry: P(r), ds(r), V(r) ----
        "s_waitcnt lgkmcnt(0)\n\t"
        SMEMLD("64:79", "80:95", "s27")        // issue Q(r+1), full-einsum lead
        EINSM_P
        EIN_TAIL                               // b32+b48; issues V(r+1) inside
        DSLD5                                  // issue ds(r+1)
        FINX("s26")
        // ---- row r+1 (odd, buffer Q) ----
        "s_waitcnt lgkmcnt(0)\n\t"
        SMEMLD("32:47", "48:63", "s26")        // issue P(r+2)
        EINSM_Q
        EIN_TAIL                               // issues V(r+2)
        DSLD5                                  // issue ds(r+2)
        FINX("s27")
        "s_add_u32 s24, s24, 1\n\t"
        "s_cmp_lg_u32 s24, 128\n\t"
        "s_cbranch_scc1 Ltop_%=\n\t"
        "s_waitcnt vmcnt(0) lgkmcnt(0)\n\t"    // drain trailing prefetches
        "v_mov_b32 %[ob], v89\n\t"
        "v_mov_b32 %[oi], v90\n\t"
        : [ob] "=v"(best), [oi] "=v"(bidx)
        : [ra] "v"(ra), [cb] "s"(cbw), [c2] "s"(c2w), [m0] "s"(m0),
          [lb] "s"(ldsbase), [lc] "s"(ldsclamp)
        : "vcc", "scc",
          "s24","s25","s26","s27","s29","s30",
          "s32","s33","s34","s35","s36","s37","s38","s39",
          "s40","s41","s42","s43","s44","s45","s46","s47","s48","s49","s50","s51",
          "s52","s53","s54","s55","s56","s57","s58","s59","s60","s61","s62","s63",
          "s64","s65","s66","s67","s68","s69","s70","s71","s72","s73","s74","s75",
          "s76","s77","s78","s79","s80","s81","s82","s83","s84","s85","s86","s87",
          "s88","s89","s90","s91","s92","s93","s94","s95",
          "v16","v17","v18","v19","v20","v21","v22","v23","v24","v25","v26","v27",
          "v28","v29","v30","v31","v32","v33","v34","v35","v36","v37","v38","v39",
          "v40","v41","v42","v43","v44","v45","v46","v47","v48","v49","v50","v51",
          "v52","v53","v54","v55","v56","v57","v58","v59","v60","v61","v62","v63",
          "v64","v65","v66","v67","v68","v69","v70","v71","v72","v73","v74","v75",
          "v76","v77","v78","v79","v80","v81","v82","v83","v84","v85","v86","v87",
          "v88","v89","v90","v91","v92","v93","v94","v95","v96","v97","v98","v99",
          "v100","v101","v102","v103","v104","v105","v106","v107","v108","v109",
          "v110","v111","v112","v113","v114","v115","v116","v117","v118","v119",
          "v120","v121","v122","v123","v124","v125","v126","v127");

    // ---- cross-chunk combine: u64-min over {d2_bits, m}. d2 > 0 always, so
    // u64 order == (d2, then m) == reference first-occurrence semantics.
    unsigned long long key =
        ((unsigned long long)__float_as_uint(best) << 32) | (unsigned int)bidx;
    atomicMin(&keys[point], key);
}

// ---- update: unpack winner, write idx, residual update, key reset ----
// grid = QSIZE/256. Block covers 4 points x 64 dims.
__global__ __launch_bounds__(256) void rvq_update(const float* __restrict__ res_in,
                                                  float* __restrict__ res_out,
                                                  const float* __restrict__ x,
                                                  const float* __restrict__ cbk,  // (M,D)
                                                  unsigned long long* __restrict__ keys,
                                                  float* __restrict__ idx_out,
                                                  int last) {
#pragma clang fp contract(off)
    __shared__ unsigned long long sk[4];
    const int tid = threadIdx.x;
    const int e = blockIdx.x * 256 + tid;
    const int p0 = blockIdx.x * 4;
    if (tid < 4) {
        unsigned long long k = keys[p0 + tid];
        sk[tid] = k;
        keys[p0 + tid] = ~0ULL;                       // reset for next step
        idx_out[p0 + tid] = (float)(unsigned int)k;   // exact for m < 2^24
    }
    __syncthreads();
    const int pi = tid >> 6;
    const int d = tid & 63;
    const int m = (int)(unsigned int)sk[pi];
    const float r = res_in[e] - cbk[(size_t)m * DD + d];  // exact fp32 sub
    if (last) res_out[e] = x[e] - r;   // quant = fl(x - fl(res - cb)); alias-safe
    else      res_out[e] = r;
}

extern "C" void kernel_launch(void* const* d_in, const int* in_sizes, int n_in,
                              void* d_out, int out_size, void* d_ws, size_t ws_size,
                              hipStream_t stream) {
    const float* x  = (const float*)d_in[0];
    const float* cb = (const float*)d_in[1];

    float* out = (float*)d_out;
    float* quant = out;                 // QSIZE floats
    float* idx_out = out + QSIZE;       // K*NPTS floats (indices as float)

    float* c2   = (float*)d_ws;                       // K*M floats (64 KB)
    float* res1 = c2 + (size_t)KK * MM;               // NPTS*D floats (8 MB)
    unsigned long long* keys =
        (unsigned long long*)(res1 + (size_t)QSIZE);  // NPTS u64 (256 KB)
    float* R[2] = { quant, res1 };                    // ping-pong residual

    rvq_prep<<<(KK * MM) / 256, 256, 0, stream>>>(cb, c2, keys);

    for (int k = 0; k < KK; ++k) {
        const float* rin = (k == 0) ? x : R[(k - 1) & 1];
        const int last = (k == KK - 1);
        float* rout = last ? quant : R[k & 1];
        rvq_main<<<(NPTS / PPB) * NCHUNK, PPB, 0, stream>>>(
            rin,
            cb + (size_t)k * MM * DD,
            c2 + (size_t)k * MM,
            keys);
        rvq_update<<<QSIZE / 256, 256, 0, stream>>>(
            rin, rout, x,
            cb + (size_t)k * MM * DD,
            keys,
            idx_out + (size_t)k * NPTS,
            last);
    }
}